// Round 1
// baseline (224.788 us; speedup 1.0000x reference)
//
#include <hip/hip_runtime.h>
#include <hip/hip_bf16.h>
#include <math.h>

// Problem constants (match reference)
#define B_ 16
#define L_ 256
#define A_ 128
#define D_ 4
#define H_ 64
#define DFF_ 256
#define PRED_ 64
#define COUT_ 8

// ws layout (floats)
#define WS_WZP 0        // [4][64]  W_z @ Lz_w[:64]
#define WS_BZP 256      // [64]     b_z @ Lz_w[:64] + Lz_b
#define WS_WHP 320      // [4][64]  W_h @ Lh_w[:64]
#define WS_BHP 576      // [64]     b_h @ Lh_w[:64] + Lh_b
#define WS_PART 640     // [B*L][64] per-(b,l) sum-over-agents of relu(h)

// ---------------------------------------------------------------------------
// Kernel 0: fold gate weights. Wg' = W_g @ Lg_w[0:64,:], bg' = b_g@Lg_w + Lg_b
// (the R gate multiplies zeros in the reference and is dropped entirely)
// ---------------------------------------------------------------------------
__global__ __launch_bounds__(256) void precomp_kernel(
    const float* __restrict__ W_z, const float* __restrict__ b_z,
    const float* __restrict__ W_h, const float* __restrict__ b_h,
    const float* __restrict__ Lz_w, const float* __restrict__ Lz_b,
    const float* __restrict__ Lh_w, const float* __restrict__ Lh_b,
    float* __restrict__ ws)
{
    int t = threadIdx.x;
    // 2 gates * 4 d * 64 j = 512 weight entries
    for (int idx = t; idx < 512; idx += 256) {
        int g = idx >> 8;          // 0 = z, 1 = h
        int d = (idx >> 6) & 3;
        int j = idx & 63;
        const float* W  = g ? W_h  : W_z;
        const float* Lw = g ? Lh_w : Lz_w;
        float acc = 0.f;
        for (int h = 0; h < 64; ++h)
            acc += W[d * 64 + h] * Lw[h * 64 + j];
        ws[(g ? WS_WHP : WS_WZP) + d * 64 + j] = acc;
    }
    // 2 * 64 bias entries
    if (t < 128) {
        int g = t >> 6;
        int j = t & 63;
        const float* bg = g ? b_h  : b_z;
        const float* Lw = g ? Lh_w : Lz_w;
        const float* Lb = g ? Lh_b : Lz_b;
        float acc = Lb[j];
        for (int h = 0; h < 64; ++h)
            acc += bg[h] * Lw[h * 64 + j];
        ws[(g ? WS_BHP : WS_BZP) + j] = acc;
    }
}

// ---------------------------------------------------------------------------
// Kernel 1: one block per (b,l). Builds the normalized adjacency implicitly,
// contracts with X first (D=4), then the folded [4->64] gate matvecs.
//   M[a][d]  = sum_e w[a][e]*dinv[e]*xr[e][d]
//   zp[a][j] = dinv[a]*dot4(M[a], Wz'[:,j]) + bz'[j]   (hp analogous)
//   h[a][j]  = relu((1-sigmoid(zp))*tanh(hp))
//   part[bl][j] = sum_a h[a][j]
// ---------------------------------------------------------------------------
__global__ __launch_bounds__(256) void tgcn_kernel(
    const float* __restrict__ x,
    const float* __restrict__ ws_w,
    float* __restrict__ part)
{
    __shared__ float xr_s[128][4];
    __shared__ float xs_s[128][4];     // dinv[e]*xr[e][d]
    __shared__ float sq_s[128];
    __shared__ float dinv_s[128];
    __shared__ float wz_s[4][64];
    __shared__ float wh_s[4][64];
    __shared__ float bz_s[64];
    __shared__ float bh_s[64];
    __shared__ float red_s[4][64];
    __shared__ float w_s[128][129];    // +1 pad: column-phase access is 2-way max
    float* h_s = &w_s[0][0];           // overlay after w no longer needed, [128][65]

    const int t  = threadIdx.x;
    const int bl = blockIdx.x;
    const float* xp = x + (size_t)bl * (A_ * D_);

    for (int i = t; i < 512; i += 256) xr_s[i >> 2][i & 3] = xp[i];
    wz_s[t >> 6][t & 63] = ws_w[WS_WZP + t];
    wh_s[t >> 6][t & 63] = ws_w[WS_WHP + t];
    if (t < 64) { bz_s[t] = ws_w[WS_BZP + t]; bh_s[t] = ws_w[WS_BHP + t]; }
    __syncthreads();

    if (t < 128) {
        float v0 = xr_s[t][0], v1 = xr_s[t][1], v2 = xr_s[t][2], v3 = xr_s[t][3];
        sq_s[t] = v0*v0 + v1*v1 + v2*v2 + v3*v3;
    }
    __syncthreads();

    // --- pairwise weights + row sums: 2 threads per row a, 64 cols each ---
    const int a = t >> 1, half = t & 1, e0 = half << 6;
    const float xa0 = xr_s[a][0], xa1 = xr_s[a][1], xa2 = xr_s[a][2], xa3 = xr_s[a][3];
    const float sqa = sq_s[a];
    float rs = 0.f;
    for (int k = 0; k < 64; ++k) {
        int e = e0 + k;
        float wv;
        if (e == a) {
            wv = 1.0e6f;                       // SELF_W = 1/EPS
        } else {
            float d2 = sqa + sq_s[e]
                     - 2.f * (xa0*xr_s[e][0] + xa1*xr_s[e][1]
                            + xa2*xr_s[e][2] + xa3*xr_s[e][3]);
            d2 = fmaxf(d2, 0.f);
            wv = 1.f / (sqrtf(d2) + 1e-6f);
        }
        w_s[a][e] = wv;
        rs += wv;
    }
    rs += __shfl_xor(rs, 1);                   // combine the two half-rows
    if (half == 0) dinv_s[a] = 1.f / sqrtf(rs);
    __syncthreads();

    if (t < 128) {
        float di = dinv_s[t];
        xs_s[t][0] = di * xr_s[t][0]; xs_s[t][1] = di * xr_s[t][1];
        xs_s[t][2] = di * xr_s[t][2]; xs_s[t][3] = di * xr_s[t][3];
    }
    __syncthreads();

    // --- M[a][0..3] = w_row . xs, split over the two half-rows ---
    float m0 = 0.f, m1 = 0.f, m2 = 0.f, m3 = 0.f;
    for (int k = 0; k < 64; ++k) {
        int e = e0 + k;
        float wv = w_s[a][e];
        m0 += wv * xs_s[e][0]; m1 += wv * xs_s[e][1];
        m2 += wv * xs_s[e][2]; m3 += wv * xs_s[e][3];
    }
    m0 += __shfl_xor(m0, 1); m1 += __shfl_xor(m1, 1);
    m2 += __shfl_xor(m2, 1); m3 += __shfl_xor(m3, 1);
    const float scale = dinv_s[a];
    __syncthreads();   // everyone done reading w_s before h_s overlay writes

    // --- fused gates: each pair-thread handles 32 of the 64 hidden units ---
    const int j0 = half << 5;
    for (int jj = 0; jj < 32; ++jj) {
        int j = j0 + jj;
        float zp = bz_s[j] + scale * (m0*wz_s[0][j] + m1*wz_s[1][j]
                                    + m2*wz_s[2][j] + m3*wz_s[3][j]);
        float hp = bh_s[j] + scale * (m0*wh_s[0][j] + m1*wh_s[1][j]
                                    + m2*wh_s[2][j] + m3*wh_s[3][j]);
        float z  = 1.f / (1.f + expf(-zp));
        float th = tanhf(hp);
        float hv = (1.f - z) * th;
        h_s[a * 65 + j] = fmaxf(hv, 0.f);      // pad-65 keeps banks spread
    }
    __syncthreads();

    // --- deterministic reduction over agents ---
    {
        int j = t & 63, g = t >> 6;
        float s = 0.f;
        for (int aa = g * 32; aa < g * 32 + 32; ++aa) s += h_s[aa * 65 + j];
        red_s[g][j] = s;
    }
    __syncthreads();
    if (t < 64)
        part[(size_t)bl * 64 + t] = red_s[0][t] + red_s[1][t] + red_s[2][t] + red_s[3][t];
}

// ---------------------------------------------------------------------------
// Kernel 2: per-batch reduce over L, then the tiny decoder 64->256->512.
// ---------------------------------------------------------------------------
__global__ __launch_bounds__(256) void dec_kernel(
    const float* __restrict__ part,
    const float* __restrict__ D1_w, const float* __restrict__ D1_b,
    const float* __restrict__ D2_w, const float* __restrict__ D2_b,
    float* __restrict__ out)
{
    __shared__ float red_s[4][64];
    __shared__ float pooled_s[64];
    __shared__ float t1_s[256];
    const int t = threadIdx.x, b = blockIdx.x;

    {
        int j = t & 63, g = t >> 6;
        const float* pb = part + (size_t)b * L_ * 64;
        float s = 0.f;
        for (int l = g * 64; l < g * 64 + 64; ++l) s += pb[l * 64 + j];
        red_s[g][j] = s;
    }
    __syncthreads();
    if (t < 64)
        pooled_s[t] = (red_s[0][t] + red_s[1][t] + red_s[2][t] + red_s[3][t])
                      * (1.f / ((float)L_ * (float)A_));
    __syncthreads();

    {
        float acc = D1_b[t];
        for (int h = 0; h < 64; ++h) acc += pooled_s[h] * D1_w[h * 256 + t];
        t1_s[t] = fmaxf(acc, 0.f);
    }
    __syncthreads();

    for (int m = t; m < 512; m += 256) {
        float acc = D2_b[m];
        for (int k = 0; k < 256; ++k) acc += t1_s[k] * D2_w[k * 512 + m];
        out[(size_t)b * 512 + m] = acc;
    }
}

// ---------------------------------------------------------------------------
extern "C" void kernel_launch(void* const* d_in, const int* in_sizes, int n_in,
                              void* d_out, int out_size, void* d_ws, size_t ws_size,
                              hipStream_t stream)
{
    const float* x    = (const float*)d_in[0];
    // d_in[1..3]: x_mark_enc, x_dec, x_mark_dec — unused by the reference
    const float* W_z  = (const float*)d_in[4];
    const float* b_z  = (const float*)d_in[5];
    // d_in[6], d_in[7]: W_r, b_r — dead code in the reference (R multiplies zeros)
    const float* W_h  = (const float*)d_in[8];
    const float* b_h  = (const float*)d_in[9];
    const float* Lz_w = (const float*)d_in[10];
    const float* Lz_b = (const float*)d_in[11];
    // d_in[12], d_in[13]: Lr_w, Lr_b — dead
    const float* Lh_w = (const float*)d_in[14];
    const float* Lh_b = (const float*)d_in[15];
    const float* D1_w = (const float*)d_in[16];
    const float* D1_b = (const float*)d_in[17];
    const float* D2_w = (const float*)d_in[18];
    const float* D2_b = (const float*)d_in[19];

    float* ws  = (float*)d_ws;
    float* out = (float*)d_out;

    precomp_kernel<<<1, 256, 0, stream>>>(W_z, b_z, W_h, b_h,
                                          Lz_w, Lz_b, Lh_w, Lh_b, ws);
    tgcn_kernel<<<B_ * L_, 256, 0, stream>>>(x, ws, ws + WS_PART);
    dec_kernel<<<B_, 256, 0, stream>>>(ws + WS_PART, D1_w, D1_b, D2_w, D2_b, out);
}

// Round 2
// 120.653 us; speedup vs baseline: 1.8631x; 1.8631x over previous
//
#include <hip/hip_runtime.h>
#include <hip/hip_bf16.h>
#include <math.h>

// Problem constants (match reference)
#define B_ 16
#define L_ 256
#define A_ 128
#define D_ 4
#define H_ 64
#define DFF_ 256
#define PRED_ 64
#define COUT_ 8

// ws layout (floats)
#define WS_WZP 0        // [64][4]  (W_z @ Lz_w[:64]) TRANSPOSED: [j][d]
#define WS_BZP 256      // [64]     b_z @ Lz_w[:64] + Lz_b
#define WS_WHP 320      // [64][4]  (W_h @ Lh_w[:64]) TRANSPOSED: [j][d]
#define WS_BHP 576      // [64]     b_h @ Lh_w[:64] + Lh_b
#define WS_PART 640     // [B*L][64] per-(b,l) sum-over-agents of relu(h)

#define L2E 1.4426950408889634f

// ---------------------------------------------------------------------------
// Kernel 0: fold gate weights. Wg' = W_g @ Lg_w[0:64,:] stored [j][4],
// bg' = b_g@Lg_w + Lg_b.  (R gate multiplies zeros in the reference: dropped)
// ---------------------------------------------------------------------------
__global__ __launch_bounds__(256) void precomp_kernel(
    const float* __restrict__ W_z, const float* __restrict__ b_z,
    const float* __restrict__ W_h, const float* __restrict__ b_h,
    const float* __restrict__ Lz_w, const float* __restrict__ Lz_b,
    const float* __restrict__ Lh_w, const float* __restrict__ Lh_b,
    float* __restrict__ ws)
{
    int t = threadIdx.x;
    // 2 gates * 4 d * 64 j = 512 weight entries
    for (int idx = t; idx < 512; idx += 256) {
        int g = idx >> 8;          // 0 = z, 1 = h
        int d = (idx >> 6) & 3;
        int j = idx & 63;
        const float* W  = g ? W_h  : W_z;
        const float* Lw = g ? Lh_w : Lz_w;
        float acc = 0.f;
        for (int h = 0; h < 64; ++h)
            acc += W[d * 64 + h] * Lw[h * 64 + j];
        ws[(g ? WS_WHP : WS_WZP) + j * 4 + d] = acc;   // transposed store
    }
    // 2 * 64 bias entries
    if (t < 128) {
        int g = t >> 6;
        int j = t & 63;
        const float* bg = g ? b_h  : b_z;
        const float* Lw = g ? Lh_w : Lz_w;
        const float* Lb = g ? Lh_b : Lz_b;
        float acc = Lb[j];
        for (int h = 0; h < 64; ++h)
            acc += bg[h] * Lw[h * 64 + j];
        ws[(g ? WS_BHP : WS_BZP) + j] = acc;
    }
}

// ---------------------------------------------------------------------------
// Kernel 1: one block per (b,l).
//   w[a][e] = min(rsq(||xa-xe||^2), 1e6)  (symmetric: triangle only + mirror)
//   dinv[a] = rsq(sum_e w[a][e])
//   M[a][d] = sum_e w[a][e]*dinv[e]*xr[e][d]; then m *= dinv[a]
//   zp = m.Wz'+bz'; hp = m.Wh'+bh'
//   h  = relu((1-sigmoid(zp))*tanh(hp));  part[bl][j] = sum_a h[a][j]
// ---------------------------------------------------------------------------
__global__ __launch_bounds__(256) void tgcn_kernel(
    const float* __restrict__ x,
    const float* __restrict__ ws_w,
    float* __restrict__ part)
{
    __shared__ float4 xr4_s[128];
    __shared__ float4 xs4_s[128];      // dinv[e]*xr[e]
    __shared__ float  sq_s[128];
    __shared__ float  dinv_s[128];
    __shared__ float4 wz4_s[64];
    __shared__ float4 wh4_s[64];
    __shared__ float  bz_s[64];
    __shared__ float  bh_s[64];
    __shared__ float  red_s[4][64];
    __shared__ float  w_s[128 * 129];  // pad 129: reads 2-way, writes <=4-way
    float* h_s = w_s;                  // overlay after w no longer needed, [128][65]

    const int t  = threadIdx.x;
    const int bl = blockIdx.x;

    // ---- stage inputs ----
    const float4* xp4 = (const float4*)(x + (size_t)bl * (A_ * D_));
    if (t < 128) xr4_s[t] = xp4[t];
    if (t < 64)        wz4_s[t]       = ((const float4*)(ws_w + WS_WZP))[t];
    else if (t < 128)  wh4_s[t - 64]  = ((const float4*)(ws_w + WS_WHP))[t - 64];
    else if (t < 192)  bz_s[t - 128]  = ws_w[WS_BZP + (t - 128)];
    else               bh_s[t - 192]  = ws_w[WS_BHP + (t - 192)];
    __syncthreads();

    if (t < 128) {
        float4 v = xr4_s[t];
        sq_s[t] = v.x * v.x + v.y * v.y + v.z * v.z + v.w * v.w;
    }
    __syncthreads();

    // ---- pairwise weights, upper triangle via cyclic offsets + mirror ----
    // waves 0-1 (t<128): odd o in 1..63 (32 iters), a = t
    // waves 2-3       : even o in 2..62 (31 iters) + o=64 for a<64, a = t-128
    {
        const int a = t & 127;
        const float4 xa = xr4_s[a];
        const float sqa = sq_s[a];
        if (t < 128) w_s[a * 129 + a] = 1.0e6f;    // SELF_W = 1/EPS
        const bool oddg = (t < 128);
        for (int i = 0; i < 32; ++i) {
            int o; bool active = true;
            if (oddg) o = 1 + 2 * i;
            else if (i < 31) o = 2 + 2 * i;
            else { o = 64; active = (a < 64); }    // wave-uniform mask
            if (active) {
                int e = (a + o) & 127;
                float4 xe = xr4_s[e];
                float d2 = sqa + sq_s[e]
                         - 2.f * (xa.x * xe.x + xa.y * xe.y
                                + xa.z * xe.z + xa.w * xe.w);
                float wv = fminf(__builtin_amdgcn_rsqf(fmaxf(d2, 0.f)), 1.0e6f);
                w_s[a * 129 + e] = wv;
                w_s[e * 129 + a] = wv;
            }
        }
    }
    __syncthreads();

    // ---- row sums -> dinv (2 threads per row) ----
    const int r  = t >> 1;
    const int hf = t & 1;
    const int e0 = hf << 6;
    {
        float rs = 0.f;
        for (int k = 0; k < 64; ++k) rs += w_s[r * 129 + e0 + k];
        rs += __shfl_xor(rs, 1);
        if (hf == 0) dinv_s[r] = __builtin_amdgcn_rsqf(rs);
    }
    __syncthreads();

    if (t < 128) {
        float di = dinv_s[t];
        float4 v = xr4_s[t];
        xs4_s[t] = make_float4(di * v.x, di * v.y, di * v.z, di * v.w);
    }
    __syncthreads();

    // ---- M[a][0..3] = w_row . xs (split over halves) ----
    float m0 = 0.f, m1 = 0.f, m2 = 0.f, m3 = 0.f;
    for (int k = 0; k < 64; ++k) {
        int e = e0 + k;
        float wv = w_s[r * 129 + e];
        float4 u = xs4_s[e];
        m0 += wv * u.x; m1 += wv * u.y; m2 += wv * u.z; m3 += wv * u.w;
    }
    m0 += __shfl_xor(m0, 1); m1 += __shfl_xor(m1, 1);
    m2 += __shfl_xor(m2, 1); m3 += __shfl_xor(m3, 1);
    {
        const float scale = dinv_s[r];
        m0 *= scale; m1 *= scale; m2 *= scale; m3 *= scale;
    }
    __syncthreads();   // all w_s reads done before h_s overlay writes

    // ---- fused gates, fast transcendentals ----
    {
        const int j0 = hf << 5;
        for (int jj = 0; jj < 32; ++jj) {
            int j = j0 + jj;
            float4 wz = wz4_s[j];
            float4 wh = wh4_s[j];
            float zp = bz_s[j] + m0 * wz.x + m1 * wz.y + m2 * wz.z + m3 * wz.w;
            float hp = bh_s[j] + m0 * wh.x + m1 * wh.y + m2 * wh.z + m3 * wh.w;
            // 1 - sigmoid(zp) = 1/(1+e^zp); tanh(hp) = 1 - 2/(1+e^{2 hp})
            float ez  = __builtin_amdgcn_exp2f(zp * L2E);
            float omz = __builtin_amdgcn_rcpf(1.f + ez);
            float e2  = __builtin_amdgcn_exp2f(hp * (2.f * L2E));
            float th  = 1.f - 2.f * __builtin_amdgcn_rcpf(1.f + e2);
            h_s[r * 65 + j] = fmaxf(omz * th, 0.f);
        }
    }
    __syncthreads();

    // ---- deterministic reduction over agents ----
    {
        int j = t & 63, g = t >> 6;
        float s = 0.f;
        for (int aa = g * 32; aa < g * 32 + 32; ++aa) s += h_s[aa * 65 + j];
        red_s[g][j] = s;
    }
    __syncthreads();
    if (t < 64)
        part[(size_t)bl * 64 + t] = red_s[0][t] + red_s[1][t] + red_s[2][t] + red_s[3][t];
}

// ---------------------------------------------------------------------------
// Kernel 2: per-batch reduce over L, then the tiny decoder 64->256->512.
// ---------------------------------------------------------------------------
__global__ __launch_bounds__(256) void dec_kernel(
    const float* __restrict__ part,
    const float* __restrict__ D1_w, const float* __restrict__ D1_b,
    const float* __restrict__ D2_w, const float* __restrict__ D2_b,
    float* __restrict__ out)
{
    __shared__ float red_s[4][64];
    __shared__ float pooled_s[64];
    __shared__ float t1_s[256];
    const int t = threadIdx.x, b = blockIdx.x;

    {
        int j = t & 63, g = t >> 6;
        const float* pb = part + (size_t)b * L_ * 64;
        float s = 0.f;
        for (int l = g * 64; l < g * 64 + 64; ++l) s += pb[l * 64 + j];
        red_s[g][j] = s;
    }
    __syncthreads();
    if (t < 64)
        pooled_s[t] = (red_s[0][t] + red_s[1][t] + red_s[2][t] + red_s[3][t])
                      * (1.f / ((float)L_ * (float)A_));
    __syncthreads();

    {
        float acc = D1_b[t];
        for (int h = 0; h < 64; ++h) acc += pooled_s[h] * D1_w[h * 256 + t];
        t1_s[t] = fmaxf(acc, 0.f);
    }
    __syncthreads();

    for (int m = t; m < 512; m += 256) {
        float acc = D2_b[m];
        for (int k = 0; k < 256; ++k) acc += t1_s[k] * D2_w[k * 512 + m];
        out[(size_t)b * 512 + m] = acc;
    }
}

// ---------------------------------------------------------------------------
extern "C" void kernel_launch(void* const* d_in, const int* in_sizes, int n_in,
                              void* d_out, int out_size, void* d_ws, size_t ws_size,
                              hipStream_t stream)
{
    const float* x    = (const float*)d_in[0];
    // d_in[1..3]: x_mark_enc, x_dec, x_mark_dec — unused by the reference
    const float* W_z  = (const float*)d_in[4];
    const float* b_z  = (const float*)d_in[5];
    // d_in[6], d_in[7]: W_r, b_r — dead code in the reference (R multiplies zeros)
    const float* W_h  = (const float*)d_in[8];
    const float* b_h  = (const float*)d_in[9];
    const float* Lz_w = (const float*)d_in[10];
    const float* Lz_b = (const float*)d_in[11];
    // d_in[12], d_in[13]: Lr_w, Lr_b — dead
    const float* Lh_w = (const float*)d_in[14];
    const float* Lh_b = (const float*)d_in[15];
    const float* D1_w = (const float*)d_in[16];
    const float* D1_b = (const float*)d_in[17];
    const float* D2_w = (const float*)d_in[18];
    const float* D2_b = (const float*)d_in[19];

    float* ws  = (float*)d_ws;
    float* out = (float*)d_out;

    precomp_kernel<<<1, 256, 0, stream>>>(W_z, b_z, W_h, b_h,
                                          Lz_w, Lz_b, Lh_w, Lh_b, ws);
    tgcn_kernel<<<B_ * L_, 256, 0, stream>>>(x, ws, ws + WS_PART);
    dec_kernel<<<B_, 256, 0, stream>>>(ws + WS_PART, D1_w, D1_b, D2_w, D2_b, out);
}

// Round 3
// 94.168 us; speedup vs baseline: 2.3871x; 1.2813x over previous
//
#include <hip/hip_runtime.h>
#include <hip/hip_bf16.h>
#include <math.h>

// Problem constants (match reference)
#define B_ 16
#define L_ 256
#define A_ 128
#define D_ 4
#define H_ 64
#define DFF_ 256
#define PRED_ 64
#define COUT_ 8

// ws layout (floats)
#define WS_WZP 0        // [64][4]  (W_z @ Lz_w[:64]) TRANSPOSED: [j][d]
#define WS_BZP 256      // [64]     b_z @ Lz_w[:64] + Lz_b
#define WS_WHP 320      // [64][4]  (W_h @ Lh_w[:64]) TRANSPOSED: [j][d]
#define WS_BHP 576      // [64]     b_h @ Lh_w[:64] + Lh_b
#define WS_PART 640     // [B*L][64] per-(b,l) sum-over-agents of relu(h)

#define L2E 1.4426950408889634f

// ---------------------------------------------------------------------------
// Kernel 0: fold gate weights. Wg' = W_g @ Lg_w[0:64,:] stored [j][4],
// bg' = b_g@Lg_w + Lg_b.  (R gate multiplies zeros in the reference: dropped)
// ---------------------------------------------------------------------------
__global__ __launch_bounds__(256) void precomp_kernel(
    const float* __restrict__ W_z, const float* __restrict__ b_z,
    const float* __restrict__ W_h, const float* __restrict__ b_h,
    const float* __restrict__ Lz_w, const float* __restrict__ Lz_b,
    const float* __restrict__ Lh_w, const float* __restrict__ Lh_b,
    float* __restrict__ ws)
{
    int t = threadIdx.x;
    for (int idx = t; idx < 512; idx += 256) {
        int g = idx >> 8;          // 0 = z, 1 = h
        int d = (idx >> 6) & 3;
        int j = idx & 63;
        const float* W  = g ? W_h  : W_z;
        const float* Lw = g ? Lh_w : Lz_w;
        float acc = 0.f;
        for (int h = 0; h < 64; ++h)
            acc += W[d * 64 + h] * Lw[h * 64 + j];
        ws[(g ? WS_WHP : WS_WZP) + j * 4 + d] = acc;   // transposed store
    }
    if (t < 128) {
        int g = t >> 6;
        int j = t & 63;
        const float* bg = g ? b_h  : b_z;
        const float* Lw = g ? Lh_w : Lz_w;
        const float* Lb = g ? Lh_b : Lz_b;
        float acc = Lb[j];
        for (int h = 0; h < 64; ++h)
            acc += bg[h] * Lw[h * 64 + j];
        ws[(g ? WS_BHP : WS_BZP) + j] = acc;
    }
}

// ---------------------------------------------------------------------------
// Kernel 1: one block per (b,l). No w matrix in LDS: each thread owns a
// 64-column half-row strip, caches w in 64 VGPRs between the rowsum pass and
// the M pass. All LDS reads are wave-broadcast (conflict-free).
//   w(r,e)  = min(rsq(|xr[r]-xr[e]|^2), 1e6)   (diag exact: rsq(0)->inf->1e6)
//   dinv[r] = rsq(sum_e w(r,e))
//   m[r]    = dinv[r] * sum_e w(r,e)*dinv[e]*xr[e]
//   h[r][j] = relu((1-sigmoid(m.wz'+bz'))*tanh(m.wh'+bh'))
//   part[bl][j] = sum_r h[r][j]
// ---------------------------------------------------------------------------
__global__ __launch_bounds__(256, 3) void tgcn_kernel(
    const float* __restrict__ x,
    const float* __restrict__ ws_w,
    float* __restrict__ part)
{
    __shared__ float4 xr4_s[128];     // agent features
    __shared__ float4 xs4_s[128];     // dinv[e]*xr[e]
    __shared__ float4 M4_s[128];      // per-row m (pre-scaled by dinv[r])
    __shared__ float4 wz4_s[64];
    __shared__ float4 wh4_s[64];
    __shared__ float  bz_s[64];
    __shared__ float  bh_s[64];
    __shared__ float  red_s[4][64];

    const int t  = threadIdx.x;
    const int bl = blockIdx.x;

    // ---- stage ----
    if (t < 128) {
        xr4_s[t] = ((const float4*)(x + (size_t)bl * (A_ * D_)))[t];
    } else {
        int i = t - 128;
        if (i < 64) wz4_s[i]      = ((const float4*)(ws_w + WS_WZP))[i];
        else        wh4_s[i - 64] = ((const float4*)(ws_w + WS_WHP))[i - 64];
        bz_s[i & 63] = (i < 64) ? ws_w[WS_BZP + i] : 0.f;   // placeholder, fixed below
    }
    // biases: simple second assignment by upper half
    if (t >= 128) {
        int i = t - 128;
        if (i < 64) bz_s[i]      = ws_w[WS_BZP + i];
        else        bh_s[i - 64] = ws_w[WS_BHP + (i - 64)];
    }
    __syncthreads();

    const int r  = t >> 1;          // row (agent) 0..127
    const int hf = t & 1;           // which 64-column half
    const int e0 = hf << 6;

    const float4 xa = xr4_s[r];

    // ---- pass 1: w strip in registers + rowsum ----
    float wreg[64];
    float rs0 = 0.f, rs1 = 0.f;
    #pragma unroll
    for (int k = 0; k < 64; ++k) {
        float4 xe = xr4_s[e0 + k];             // broadcast read
        float dx = xa.x - xe.x, dy = xa.y - xe.y;
        float dz = xa.z - xe.z, dw = xa.w - xe.w;
        float d2 = dx * dx + dy * dy + dz * dz + dw * dw;
        float wv = fminf(__builtin_amdgcn_rsqf(d2), 1.0e6f);
        wreg[k] = wv;
        if (k & 1) rs1 += wv; else rs0 += wv;
    }
    float rs = rs0 + rs1;
    rs += __shfl_xor(rs, 1);                   // combine halves (lane pair)
    const float dinv = __builtin_amdgcn_rsqf(rs);
    if (hf == 0)
        xs4_s[r] = make_float4(dinv * xa.x, dinv * xa.y, dinv * xa.z, dinv * xa.w);
    __syncthreads();

    // ---- pass 2: m = w_row . xs ----
    float m0 = 0.f, m1 = 0.f, m2 = 0.f, m3 = 0.f;
    #pragma unroll
    for (int k = 0; k < 64; ++k) {
        float4 u = xs4_s[e0 + k];              // broadcast read
        float wv = wreg[k];
        m0 += wv * u.x; m1 += wv * u.y; m2 += wv * u.z; m3 += wv * u.w;
    }
    m0 += __shfl_xor(m0, 1); m1 += __shfl_xor(m1, 1);
    m2 += __shfl_xor(m2, 1); m3 += __shfl_xor(m3, 1);
    if (hf == 0)
        M4_s[r] = make_float4(dinv * m0, dinv * m1, dinv * m2, dinv * m3);
    __syncthreads();

    // ---- gates, transposed: thread <-> column j, loop over agents ----
    {
        const int j = t & 63;
        const int g = t >> 6;                  // wave id -> agent quarter
        const float4 wz = wz4_s[j];
        const float4 wh = wh4_s[j];
        const float bzv = bz_s[j];
        const float bhv = bh_s[j];
        float acc = 0.f;
        #pragma unroll 8
        for (int i = 0; i < 32; ++i) {
            float4 mv = M4_s[g * 32 + i];      // broadcast read
            float zp = bzv + mv.x * wz.x + mv.y * wz.y + mv.z * wz.z + mv.w * wz.w;
            float hp = bhv + mv.x * wh.x + mv.y * wh.y + mv.z * wh.z + mv.w * wh.w;
            // (1 - sigmoid(zp)) = 1/(1+e^zp); tanh(hp) = 1 - 2/(1+e^{2hp})
            float ez  = __builtin_amdgcn_exp2f(zp * L2E);
            float omz = __builtin_amdgcn_rcpf(1.f + ez);
            float e2  = __builtin_amdgcn_exp2f(hp * (2.f * L2E));
            float th  = 1.f - 2.f * __builtin_amdgcn_rcpf(1.f + e2);
            acc += fmaxf(omz * th, 0.f);
        }
        red_s[g][j] = acc;
    }
    __syncthreads();

    if (t < 64)
        part[(size_t)bl * 64 + t] = red_s[0][t] + red_s[1][t] + red_s[2][t] + red_s[3][t];
}

// ---------------------------------------------------------------------------
// Kernel 2: per-batch reduce over L, then the tiny decoder 64->256->512.
// ---------------------------------------------------------------------------
__global__ __launch_bounds__(256) void dec_kernel(
    const float* __restrict__ part,
    const float* __restrict__ D1_w, const float* __restrict__ D1_b,
    const float* __restrict__ D2_w, const float* __restrict__ D2_b,
    float* __restrict__ out)
{
    __shared__ float red_s[4][64];
    __shared__ float pooled_s[64];
    __shared__ float t1_s[256];
    const int t = threadIdx.x, b = blockIdx.x;

    {
        int j = t & 63, g = t >> 6;
        const float* pb = part + (size_t)b * L_ * 64;
        float s = 0.f;
        for (int l = g * 64; l < g * 64 + 64; ++l) s += pb[l * 64 + j];
        red_s[g][j] = s;
    }
    __syncthreads();
    if (t < 64)
        pooled_s[t] = (red_s[0][t] + red_s[1][t] + red_s[2][t] + red_s[3][t])
                      * (1.f / ((float)L_ * (float)A_));
    __syncthreads();

    {
        float acc = D1_b[t];
        for (int h = 0; h < 64; ++h) acc += pooled_s[h] * D1_w[h * 256 + t];
        t1_s[t] = fmaxf(acc, 0.f);
    }
    __syncthreads();

    for (int m = t; m < 512; m += 256) {
        float acc = D2_b[m];
        for (int k = 0; k < 256; ++k) acc += t1_s[k] * D2_w[k * 512 + m];
        out[(size_t)b * 512 + m] = acc;
    }
}

// ---------------------------------------------------------------------------
extern "C" void kernel_launch(void* const* d_in, const int* in_sizes, int n_in,
                              void* d_out, int out_size, void* d_ws, size_t ws_size,
                              hipStream_t stream)
{
    const float* x    = (const float*)d_in[0];
    // d_in[1..3]: x_mark_enc, x_dec, x_mark_dec — unused by the reference
    const float* W_z  = (const float*)d_in[4];
    const float* b_z  = (const float*)d_in[5];
    // d_in[6], d_in[7]: W_r, b_r — dead code in the reference
    const float* W_h  = (const float*)d_in[8];
    const float* b_h  = (const float*)d_in[9];
    const float* Lz_w = (const float*)d_in[10];
    const float* Lz_b = (const float*)d_in[11];
    // d_in[12], d_in[13]: Lr_w, Lr_b — dead
    const float* Lh_w = (const float*)d_in[14];
    const float* Lh_b = (const float*)d_in[15];
    const float* D1_w = (const float*)d_in[16];
    const float* D1_b = (const float*)d_in[17];
    const float* D2_w = (const float*)d_in[18];
    const float* D2_b = (const float*)d_in[19];

    float* ws  = (float*)d_ws;
    float* out = (float*)d_out;

    precomp_kernel<<<1, 256, 0, stream>>>(W_z, b_z, W_h, b_h,
                                          Lz_w, Lz_b, Lh_w, Lh_b, ws);
    tgcn_kernel<<<B_ * L_, 256, 0, stream>>>(x, ws, ws + WS_PART);
    dec_kernel<<<B_, 256, 0, stream>>>(ws + WS_PART, D1_w, D1_b, D2_w, D2_b, out);
}